// Round 2
// baseline (890.853 us; speedup 1.0000x reference)
//
#include <hip/hip_runtime.h>
#include <hip/hip_bf16.h>

// bf16 MFMA fragment types (gfx950: 16x16x32, 8 bf16 inputs / 4 f32 acc per lane)
typedef __attribute__((ext_vector_type(8))) short bf16x8;
typedef __attribute__((ext_vector_type(4))) float f32x4;

#define DD 128

static __device__ __forceinline__ unsigned short f2bf(float f) {
    unsigned int u = __builtin_bit_cast(unsigned int, f);
    u += 0x7fffu + ((u >> 16) & 1u);   // RNE
    return (unsigned short)(u >> 16);
}
static __device__ __forceinline__ float bf2f(unsigned short h) {
    unsigned int u = ((unsigned int)h) << 16;
    return __builtin_bit_cast(float, u);
}

// ---------------- weight conversion: 6 matrices fp32 -> bf16 in ws ----------------
__global__ void k_convert(const float* __restrict__ w0, const float* __restrict__ w1,
                          const float* __restrict__ w2, const float* __restrict__ w3,
                          const float* __restrict__ w4, const float* __restrict__ w5,
                          unsigned short* __restrict__ wbf) {
    int i = blockIdx.x * blockDim.x + threadIdx.x;
    if (i >= 6 * 16384) return;
    int m = i >> 14, k = i & 16383;
    const float* s = (m == 0) ? w0 : (m == 1) ? w1 : (m == 2) ? w2 : (m == 3) ? w3
                     : (m == 4) ? w4 : w5;
    wbf[i] = f2bf(s[k]);
}

// ---------------- node pooling: Vp = lrelu(lrelu(V)@Wp1^T+bp1)@Wp2^T+bp2 ----------
__global__ __launch_bounds__(256, 4) void k_nodes(
    const float* __restrict__ V, const unsigned short* __restrict__ wbf,
    const float* __restrict__ bp1, const float* __restrict__ bp2,
    unsigned short* __restrict__ Vp, int nN, int nTiles)
{
    const int lane = threadIdx.x & 63;
    const int wave = threadIdx.x >> 6;     // 0..3, owns cols [wave*32, wave*32+32)
    const int lr = lane & 15, lg = lane >> 4;

    bf16x8 B1[2][4], B2[2][4];
#pragma unroll
    for (int ct = 0; ct < 2; ++ct)
#pragma unroll
        for (int kk = 0; kk < 4; ++kk) {
            int j = wave * 32 + ct * 16 + lr;
            int k0 = kk * 32 + lg * 8;
            B1[ct][kk] = *(const bf16x8*)(wbf + 0 * 16384 + j * DD + k0);
            B2[ct][kk] = *(const bf16x8*)(wbf + 1 * 16384 + j * DD + k0);
        }
    float b1v[2], b2v[2];
#pragma unroll
    for (int ct = 0; ct < 2; ++ct) {
        int c = wave * 32 + ct * 16 + lr;
        b1v[ct] = bp1[c]; b2v[ct] = bp2[c];
    }
    __shared__ alignas(16) unsigned short xb[32][136];  // +8 pad: conflict-free b128 reads

    for (int t = blockIdx.x; t < nTiles; t += gridDim.x) {
        const int r0 = t * 32;
        bf16x8 A[2][4];
#pragma unroll
        for (int rg = 0; rg < 2; ++rg)
#pragma unroll
            for (int kk = 0; kk < 4; ++kk) {
                int row = r0 + rg * 16 + lr; if (row >= nN) row = nN - 1;
                const float4* p = (const float4*)(V + (size_t)row * DD + kk * 32 + lg * 8);
                float4 f0 = p[0], f1 = p[1];
                float v[8] = {f0.x, f0.y, f0.z, f0.w, f1.x, f1.y, f1.z, f1.w};
                bf16x8 a;
#pragma unroll
                for (int e = 0; e < 8; ++e) {
                    float x = v[e];
                    x = x > 0.f ? x : 0.2f * x;     // lrelu(V) before first GEMM
                    a[e] = (short)f2bf(x);
                }
                A[rg][kk] = a;
            }
        // G1 + bias + lrelu -> LDS
#pragma unroll
        for (int rg = 0; rg < 2; ++rg)
#pragma unroll
            for (int ct = 0; ct < 2; ++ct) {
                f32x4 acc = {0.f, 0.f, 0.f, 0.f};
#pragma unroll
                for (int kk = 0; kk < 4; ++kk)
                    acc = __builtin_amdgcn_mfma_f32_16x16x32_bf16(A[rg][kk], B1[ct][kk], acc, 0, 0, 0);
#pragma unroll
                for (int r = 0; r < 4; ++r) {
                    float x = acc[r] + b1v[ct];
                    x = x > 0.f ? x : 0.2f * x;
                    xb[rg * 16 + lg * 4 + r][wave * 32 + ct * 16 + lr] = f2bf(x);
                }
            }
        __syncthreads();
        // G2 + bias -> Vp (bf16)
        bf16x8 A2[2][4];
#pragma unroll
        for (int rg = 0; rg < 2; ++rg)
#pragma unroll
            for (int kk = 0; kk < 4; ++kk)
                A2[rg][kk] = *(const bf16x8*)&xb[rg * 16 + lr][kk * 32 + lg * 8];
#pragma unroll
        for (int rg = 0; rg < 2; ++rg)
#pragma unroll
            for (int ct = 0; ct < 2; ++ct) {
                f32x4 acc = {0.f, 0.f, 0.f, 0.f};
#pragma unroll
                for (int kk = 0; kk < 4; ++kk)
                    acc = __builtin_amdgcn_mfma_f32_16x16x32_bf16(A2[rg][kk], B2[ct][kk], acc, 0, 0, 0);
#pragma unroll
                for (int r = 0; r < 4; ++r) {
                    int row = r0 + rg * 16 + lg * 4 + r;
                    if (row < nN)
                        Vp[(size_t)row * DD + wave * 32 + ct * 16 + lr] = f2bf(acc[r] + b2v[ct]);
                }
            }
        __syncthreads();   // single-buffer LDS: protect against next tile's writes
    }
}

// ---------------- fused edge pipeline + gather + scatter-sum ----------------------
__global__ __launch_bounds__(256, 4) void k_edges(
    const float* __restrict__ E, const int* __restrict__ src, const int* __restrict__ dst,
    const unsigned short* __restrict__ wbf,
    const float* __restrict__ bA1, const float* __restrict__ bA2,
    const float* __restrict__ bB, const float* __restrict__ bC,
    const unsigned short* __restrict__ Vp, float* __restrict__ out, int nE, int nTiles)
{
    const int lane = threadIdx.x & 63;
    const int wave = threadIdx.x >> 6;
    const int lr = lane & 15, lg = lane >> 4;
    // gather-staging role: 8 threads per gathered row, 4x 8B chunks each
    const int srow = threadIdx.x >> 3;     // 0..31
    const int schunk = threadIdx.x & 7;    // 0..7

    bf16x8 B1[2][4], B2[2][4], B3[2][4], B4[2][4];
#pragma unroll
    for (int ct = 0; ct < 2; ++ct)
#pragma unroll
        for (int kk = 0; kk < 4; ++kk) {
            int j = wave * 32 + ct * 16 + lr;
            int k0 = kk * 32 + lg * 8;
            const unsigned short* p = wbf + 2 * 16384 + j * DD + k0;
            B1[ct][kk] = *(const bf16x8*)(p);            // WA1
            B2[ct][kk] = *(const bf16x8*)(p + 16384);    // WA2
            B3[ct][kk] = *(const bf16x8*)(p + 32768);    // WB
            B4[ct][kk] = *(const bf16x8*)(p + 49152);    // WC
        }
    float b1v[2], b2v[2], b3v[2], b4v[2];
#pragma unroll
    for (int ct = 0; ct < 2; ++ct) {
        int c = wave * 32 + ct * 16 + lr;
        b1v[ct] = bA1[c]; b2v[ct] = bA2[c]; b3v[ct] = bB[c]; b4v[ct] = bC[c];
    }
    __shared__ alignas(16) unsigned short xb[2][32][136];
    __shared__ alignas(8)  unsigned short gv[32][132];   // gathered Vp rows (+4 pad: 2-way reads)

    for (int t = blockIdx.x; t < nTiles; t += gridDim.x) {
        const int r0 = t * 32;
        // --- issue gathered-Vp loads EARLY (consumed after barrier2) ---
        int grow = r0 + srow; if (grow >= nE) grow = nE - 1;
        const uint2* vp2 = (const uint2*)(Vp + (size_t)src[grow] * DD);
        uint2 sreg0 = vp2[schunk];
        uint2 sreg1 = vp2[schunk + 8];
        uint2 sreg2 = vp2[schunk + 16];
        uint2 sreg3 = vp2[schunk + 24];

        bf16x8 A[2][4];
#pragma unroll
        for (int rg = 0; rg < 2; ++rg)
#pragma unroll
            for (int kk = 0; kk < 4; ++kk) {
                int row = r0 + rg * 16 + lr; if (row >= nE) row = nE - 1;
                const float4* p = (const float4*)(E + (size_t)row * DD + kk * 32 + lg * 8);
                float4 f0 = p[0], f1 = p[1];
                bf16x8 a;
                a[0] = (short)f2bf(f0.x); a[1] = (short)f2bf(f0.y);
                a[2] = (short)f2bf(f0.z); a[3] = (short)f2bf(f0.w);
                a[4] = (short)f2bf(f1.x); a[5] = (short)f2bf(f1.y);
                a[6] = (short)f2bf(f1.z); a[7] = (short)f2bf(f1.w);
                A[rg][kk] = a;
            }
        int di[8]; bool val[8];
#pragma unroll
        for (int rg = 0; rg < 2; ++rg)
#pragma unroll
            for (int r = 0; r < 4; ++r) {
                int row = r0 + rg * 16 + lg * 4 + r;
                val[rg * 4 + r] = (row < nE);
                if (row >= nE) row = nE - 1;
                di[rg * 4 + r] = dst[row];
            }
        // G1: x1 = relu(E@WA1^T + bA1) -> xb[0]
#pragma unroll
        for (int rg = 0; rg < 2; ++rg)
#pragma unroll
            for (int ct = 0; ct < 2; ++ct) {
                f32x4 acc = {0.f, 0.f, 0.f, 0.f};
#pragma unroll
                for (int kk = 0; kk < 4; ++kk)
                    acc = __builtin_amdgcn_mfma_f32_16x16x32_bf16(A[rg][kk], B1[ct][kk], acc, 0, 0, 0);
#pragma unroll
                for (int r = 0; r < 4; ++r) {
                    float x = fmaxf(acc[r] + b1v[ct], 0.f);
                    xb[0][rg * 16 + lg * 4 + r][wave * 32 + ct * 16 + lr] = f2bf(x);
                }
            }
        __syncthreads();                      // barrier1
        // park gathered rows in LDS (race-free: all waves are past G3 of tile t-1)
        *(uint2*)&gv[srow][schunk * 4]      = sreg0;
        *(uint2*)&gv[srow][schunk * 4 + 32] = sreg1;
        *(uint2*)&gv[srow][schunk * 4 + 64] = sreg2;
        *(uint2*)&gv[srow][schunk * 4 + 96] = sreg3;
        // G2: x = x1@WA2^T + bA2 -> xb[1]
        bf16x8 A2[2][4];
#pragma unroll
        for (int rg = 0; rg < 2; ++rg)
#pragma unroll
            for (int kk = 0; kk < 4; ++kk)
                A2[rg][kk] = *(const bf16x8*)&xb[0][rg * 16 + lr][kk * 32 + lg * 8];
#pragma unroll
        for (int rg = 0; rg < 2; ++rg)
#pragma unroll
            for (int ct = 0; ct < 2; ++ct) {
                f32x4 acc = {0.f, 0.f, 0.f, 0.f};
#pragma unroll
                for (int kk = 0; kk < 4; ++kk)
                    acc = __builtin_amdgcn_mfma_f32_16x16x32_bf16(A2[rg][kk], B2[ct][kk], acc, 0, 0, 0);
#pragma unroll
                for (int r = 0; r < 4; ++r)
                    xb[1][rg * 16 + lg * 4 + r][wave * 32 + ct * 16 + lr] = f2bf(acc[r] + b2v[ct]);
            }
        __syncthreads();                      // barrier2
        // G3/G4: scale = sigmoid(x@WB^T+bB), shift = x@WC^T+bC; msg; scatter
        bf16x8 A3[2][4];
#pragma unroll
        for (int rg = 0; rg < 2; ++rg)
#pragma unroll
            for (int kk = 0; kk < 4; ++kk)
                A3[rg][kk] = *(const bf16x8*)&xb[1][rg * 16 + lr][kk * 32 + lg * 8];
#pragma unroll
        for (int rg = 0; rg < 2; ++rg)
#pragma unroll
            for (int ct = 0; ct < 2; ++ct) {
                f32x4 aB = {0.f, 0.f, 0.f, 0.f}, aC = {0.f, 0.f, 0.f, 0.f};
#pragma unroll
                for (int kk = 0; kk < 4; ++kk) {
                    aB = __builtin_amdgcn_mfma_f32_16x16x32_bf16(A3[rg][kk], B3[ct][kk], aB, 0, 0, 0);
                    aC = __builtin_amdgcn_mfma_f32_16x16x32_bf16(A3[rg][kk], B4[ct][kk], aC, 0, 0, 0);
                }
                const int col = wave * 32 + ct * 16 + lr;
#pragma unroll
                for (int r = 0; r < 4; ++r) {
                    int idx = rg * 4 + r;
                    float sc = 1.f / (1.f + __expf(-(aB[r] + b3v[ct])));
                    float sh = aC[r] + b4v[ct];
                    float v = bf2f(gv[rg * 16 + lg * 4 + r][col]);
                    float msg = sc * v + sh;
                    if (val[idx])
                        unsafeAtomicAdd(out + (size_t)di[idx] * DD + col, msg);
                }
            }
        // no end-of-loop barrier needed (audited: xb/gv phases are protected by
        // barrier1/barrier2 of the NEXT iteration before any conflicting write)
    }
}

extern "C" void kernel_launch(void* const* d_in, const int* in_sizes, int n_in,
                              void* d_out, int out_size, void* d_ws, size_t ws_size,
                              hipStream_t stream) {
    const float* V   = (const float*)d_in[0];
    const float* E   = (const float*)d_in[1];
    const int*   src = (const int*)d_in[2];
    const int*   dst = (const int*)d_in[3];
    const float* Wp1 = (const float*)d_in[4];  const float* bp1 = (const float*)d_in[5];
    const float* Wp2 = (const float*)d_in[6];  const float* bp2 = (const float*)d_in[7];
    const float* WA1 = (const float*)d_in[8];  const float* bA1 = (const float*)d_in[9];
    const float* WA2 = (const float*)d_in[10]; const float* bA2 = (const float*)d_in[11];
    const float* WB  = (const float*)d_in[12]; const float* bB  = (const float*)d_in[13];
    const float* WC  = (const float*)d_in[14]; const float* bC  = (const float*)d_in[15];
    float* out = (float*)d_out;

    const int nN = in_sizes[0] / DD;
    const int nE = in_sizes[1] / DD;
    const int nTilesN = (nN + 31) / 32;
    const int nTilesE = (nE + 31) / 32;

    unsigned short* wbf = (unsigned short*)d_ws;                       // 6*16384 u16
    unsigned short* Vp  = (unsigned short*)((char*)d_ws + 196608);     // nN*128 u16

    hipMemsetAsync(d_out, 0, (size_t)out_size * sizeof(float), stream);
    k_convert<<<(6 * 16384 + 255) / 256, 256, 0, stream>>>(Wp1, Wp2, WA1, WA2, WB, WC, wbf);
    int gN = nTilesN < 1024 ? nTilesN : 1024;
    k_nodes<<<gN, 256, 0, stream>>>(V, wbf, bp1, bp2, Vp, nN, nTilesN);
    int gE = nTilesE < 4096 ? nTilesE : 4096;
    k_edges<<<gE, 256, 0, stream>>>(E, src, dst, wbf, bA1, bA2, bB, bC, Vp, out, nE, nTilesE);
}

// Round 3
// 382.121 us; speedup vs baseline: 2.3313x; 2.3313x over previous
//
#include <hip/hip_runtime.h>
#include <hip/hip_bf16.h>

// bf16 MFMA fragment types (gfx950: 16x16x32, 8 bf16 inputs / 4 f32 acc per lane)
typedef __attribute__((ext_vector_type(8))) short bf16x8;
typedef __attribute__((ext_vector_type(4))) float f32x4;

#define DD 128

static __device__ __forceinline__ unsigned short f2bf(float f) {
    unsigned int u = __builtin_bit_cast(unsigned int, f);
    u += 0x7fffu + ((u >> 16) & 1u);   // RNE
    return (unsigned short)(u >> 16);
}
static __device__ __forceinline__ unsigned int pk2bf(float lo, float hi) {
    return ((unsigned int)f2bf(hi) << 16) | (unsigned int)f2bf(lo);
}
static __device__ __forceinline__ float bf2f(unsigned short h) {
    unsigned int u = ((unsigned int)h) << 16;
    return __builtin_bit_cast(float, u);
}

// LDS-only barrier: drains LDS ops but NOT vmcnt — global loads (E prefetch,
// Vp gather) and atomic stores stay in flight across it. All cross-thread
// communication inside these kernels goes through LDS, so lgkmcnt(0) is the
// only required drain. (__syncthreads would emit s_waitcnt vmcnt(0) too.)
static __device__ __forceinline__ void lds_barrier() {
    asm volatile("s_waitcnt lgkmcnt(0)" ::: "memory");
    __builtin_amdgcn_s_barrier();
    asm volatile("" ::: "memory");
}

// ---------------- weight conversion: 6 matrices fp32 -> bf16 in ws ----------------
__global__ void k_convert(const float* __restrict__ w0, const float* __restrict__ w1,
                          const float* __restrict__ w2, const float* __restrict__ w3,
                          const float* __restrict__ w4, const float* __restrict__ w5,
                          unsigned short* __restrict__ wbf) {
    int i = blockIdx.x * blockDim.x + threadIdx.x;
    if (i >= 6 * 16384) return;
    int m = i >> 14, k = i & 16383;
    const float* s = (m == 0) ? w0 : (m == 1) ? w1 : (m == 2) ? w2 : (m == 3) ? w3
                     : (m == 4) ? w4 : w5;
    wbf[i] = f2bf(s[k]);
}

// ---------------- node pooling: Vp = lrelu(lrelu(V)@Wp1^T+bp1)@Wp2^T+bp2 ----------
__global__ __launch_bounds__(256, 2) void k_nodes(
    const float* __restrict__ V, const unsigned short* __restrict__ wbf,
    const float* __restrict__ bp1, const float* __restrict__ bp2,
    unsigned short* __restrict__ Vp, int nN, int nTiles)
{
    const int lane = threadIdx.x & 63;
    const int wave = threadIdx.x >> 6;     // 0..3, owns cols [wave*32, wave*32+32)
    const int lr = lane & 15, lg = lane >> 4;

    bf16x8 B1[2][4], B2[2][4];
#pragma unroll
    for (int ct = 0; ct < 2; ++ct)
#pragma unroll
        for (int kk = 0; kk < 4; ++kk) {
            int j = wave * 32 + ct * 16 + lr;
            int k0 = kk * 32 + lg * 8;
            B1[ct][kk] = *(const bf16x8*)(wbf + 0 * 16384 + j * DD + k0);
            B2[ct][kk] = *(const bf16x8*)(wbf + 1 * 16384 + j * DD + k0);
        }
    float b1v[2], b2v[2];
#pragma unroll
    for (int ct = 0; ct < 2; ++ct) {
        int c = wave * 32 + ct * 16 + lr;
        b1v[ct] = bp1[c]; b2v[ct] = bp2[c];
    }
    __shared__ alignas(16) unsigned short xb[32][136];  // +8 pad

    for (int t = blockIdx.x; t < nTiles; t += gridDim.x) {
        const int r0 = t * 32;
        bf16x8 A[2][4];
#pragma unroll
        for (int rg = 0; rg < 2; ++rg)
#pragma unroll
            for (int kk = 0; kk < 4; ++kk) {
                int row = r0 + rg * 16 + lr; if (row >= nN) row = nN - 1;
                const float4* p = (const float4*)(V + (size_t)row * DD + kk * 32 + lg * 8);
                float4 f0 = p[0], f1 = p[1];
                float v[8] = {f0.x, f0.y, f0.z, f0.w, f1.x, f1.y, f1.z, f1.w};
                bf16x8 a;
#pragma unroll
                for (int e = 0; e < 8; ++e) {
                    float x = v[e];
                    x = x > 0.f ? x : 0.2f * x;     // lrelu(V) before first GEMM
                    a[e] = (short)f2bf(x);
                }
                A[rg][kk] = a;
            }
        // G1 + bias + lrelu -> LDS
#pragma unroll
        for (int rg = 0; rg < 2; ++rg)
#pragma unroll
            for (int ct = 0; ct < 2; ++ct) {
                f32x4 acc = {0.f, 0.f, 0.f, 0.f};
#pragma unroll
                for (int kk = 0; kk < 4; ++kk)
                    acc = __builtin_amdgcn_mfma_f32_16x16x32_bf16(A[rg][kk], B1[ct][kk], acc, 0, 0, 0);
#pragma unroll
                for (int r = 0; r < 4; ++r) {
                    float x = acc[r] + b1v[ct];
                    x = x > 0.f ? x : 0.2f * x;
                    xb[rg * 16 + lg * 4 + r][wave * 32 + ct * 16 + lr] = f2bf(x);
                }
            }
        lds_barrier();
        // G2 + bias -> Vp (bf16)
        bf16x8 A2[2][4];
#pragma unroll
        for (int rg = 0; rg < 2; ++rg)
#pragma unroll
            for (int kk = 0; kk < 4; ++kk)
                A2[rg][kk] = *(const bf16x8*)&xb[rg * 16 + lr][kk * 32 + lg * 8];
#pragma unroll
        for (int rg = 0; rg < 2; ++rg)
#pragma unroll
            for (int ct = 0; ct < 2; ++ct) {
                f32x4 acc = {0.f, 0.f, 0.f, 0.f};
#pragma unroll
                for (int kk = 0; kk < 4; ++kk)
                    acc = __builtin_amdgcn_mfma_f32_16x16x32_bf16(A2[rg][kk], B2[ct][kk], acc, 0, 0, 0);
#pragma unroll
                for (int r = 0; r < 4; ++r) {
                    int row = r0 + rg * 16 + lg * 4 + r;
                    if (row < nN)
                        Vp[(size_t)row * DD + wave * 32 + ct * 16 + lr] = f2bf(acc[r] + b2v[ct]);
                }
            }
        lds_barrier();   // protect xb against next tile's writes
    }
}

// ---------------- fused edge pipeline + gather + scatter-sum ----------------------
__global__ __launch_bounds__(256, 2) void k_edges(
    const float* __restrict__ E, const int* __restrict__ src, const int* __restrict__ dst,
    const unsigned short* __restrict__ wbf,
    const float* __restrict__ bA1, const float* __restrict__ bA2,
    const float* __restrict__ bB, const float* __restrict__ bC,
    const unsigned short* __restrict__ Vp, float* __restrict__ out, int nE, int nTiles)
{
    const int lane = threadIdx.x & 63;
    const int wave = threadIdx.x >> 6;
    const int lr = lane & 15, lg = lane >> 4;
    // staging roles: 8 threads per row, 16 fp32 (4 float4) per thread
    const int srow = threadIdx.x >> 3;     // 0..31
    const int schunk = threadIdx.x & 7;    // 0..7

    bf16x8 B1[2][4], B2[2][4], B3[2][4], B4[2][4];
#pragma unroll
    for (int ct = 0; ct < 2; ++ct)
#pragma unroll
        for (int kk = 0; kk < 4; ++kk) {
            int j = wave * 32 + ct * 16 + lr;
            int k0 = kk * 32 + lg * 8;
            const unsigned short* p = wbf + 2 * 16384 + j * DD + k0;
            B1[ct][kk] = *(const bf16x8*)(p);            // WA1
            B2[ct][kk] = *(const bf16x8*)(p + 16384);    // WA2
            B3[ct][kk] = *(const bf16x8*)(p + 32768);    // WB
            B4[ct][kk] = *(const bf16x8*)(p + 49152);    // WC
        }
    float b1v[2], b2v[2], b3v[2], b4v[2];
#pragma unroll
    for (int ct = 0; ct < 2; ++ct) {
        int c = wave * 32 + ct * 16 + lr;
        b1v[ct] = bA1[c]; b2v[ct] = bA2[c]; b3v[ct] = bB[c]; b4v[ct] = bC[c];
    }
    __shared__ alignas(16) unsigned short xb[2][32][136];
    __shared__ alignas(16) unsigned short Eb[2][32][136];  // double-buffered bf16 E tile
    __shared__ alignas(8)  unsigned short gv[32][132];     // gathered Vp rows

    const int gstep = gridDim.x;
    int t = blockIdx.x;
    // ---- prologue: stage tile t into Eb[0] ----
    {
        int row = t * 32 + srow; if (row >= nE) row = nE - 1;
        const float4* p = (const float4*)(E + (size_t)row * DD + schunk * 16);
        float4 f0 = p[0], f1 = p[1], f2 = p[2], f3 = p[3];
        uint4 w0 = make_uint4(pk2bf(f0.x, f0.y), pk2bf(f0.z, f0.w),
                              pk2bf(f1.x, f1.y), pk2bf(f1.z, f1.w));
        uint4 w1 = make_uint4(pk2bf(f2.x, f2.y), pk2bf(f2.z, f2.w),
                              pk2bf(f3.x, f3.y), pk2bf(f3.z, f3.w));
        uint4* wp = (uint4*)&Eb[0][srow][schunk * 16];
        wp[0] = w0; wp[1] = w1;
    }
    lds_barrier();
    int cur = 0;

    for (; t < nTiles; t += gstep) {
        const int r0 = t * 32;
        // --- prefetch NEXT tile's E into regs (consumed after barrier2) ---
        int nrow = (t + gstep) * 32 + srow; if (nrow >= nE) nrow = nE - 1;
        const float4* np = (const float4*)(E + (size_t)nrow * DD + schunk * 16);
        float4 nf0 = np[0], nf1 = np[1], nf2 = np[2], nf3 = np[3];
        // --- gathered-Vp loads for THIS tile (consumed after barrier1) ---
        int grow = r0 + srow; if (grow >= nE) grow = nE - 1;
        const uint2* vp2 = (const uint2*)(Vp + (size_t)src[grow] * DD);
        uint2 g0 = vp2[schunk], g1 = vp2[schunk + 8], g2 = vp2[schunk + 16], g3 = vp2[schunk + 24];
        // --- dst indices ---
        int di[8]; bool val[8];
#pragma unroll
        for (int rg = 0; rg < 2; ++rg)
#pragma unroll
            for (int r = 0; r < 4; ++r) {
                int row = r0 + rg * 16 + lg * 4 + r;
                val[rg * 4 + r] = (row < nE);
                if (row >= nE) row = nE - 1;
                di[rg * 4 + r] = dst[row];
            }
        // --- A-frags from Eb[cur] (LDS) ---
        bf16x8 A[2][4];
#pragma unroll
        for (int rg = 0; rg < 2; ++rg)
#pragma unroll
            for (int kk = 0; kk < 4; ++kk)
                A[rg][kk] = *(const bf16x8*)&Eb[cur][rg * 16 + lr][kk * 32 + lg * 8];
        // G1: x1 = relu(E@WA1^T + bA1) -> xb[0]
#pragma unroll
        for (int rg = 0; rg < 2; ++rg)
#pragma unroll
            for (int ct = 0; ct < 2; ++ct) {
                f32x4 acc = {0.f, 0.f, 0.f, 0.f};
#pragma unroll
                for (int kk = 0; kk < 4; ++kk)
                    acc = __builtin_amdgcn_mfma_f32_16x16x32_bf16(A[rg][kk], B1[ct][kk], acc, 0, 0, 0);
#pragma unroll
                for (int r = 0; r < 4; ++r) {
                    float x = fmaxf(acc[r] + b1v[ct], 0.f);
                    xb[0][rg * 16 + lg * 4 + r][wave * 32 + ct * 16 + lr] = f2bf(x);
                }
            }
        lds_barrier();                      // barrier1
        // park gathered rows (race-free: all waves past G3 reads of tile t-1)
        *(uint2*)&gv[srow][schunk * 4]      = g0;
        *(uint2*)&gv[srow][schunk * 4 + 32] = g1;
        *(uint2*)&gv[srow][schunk * 4 + 64] = g2;
        *(uint2*)&gv[srow][schunk * 4 + 96] = g3;
        // G2: x = x1@WA2^T + bA2 -> xb[1]
        bf16x8 A2[2][4];
#pragma unroll
        for (int rg = 0; rg < 2; ++rg)
#pragma unroll
            for (int kk = 0; kk < 4; ++kk)
                A2[rg][kk] = *(const bf16x8*)&xb[0][rg * 16 + lr][kk * 32 + lg * 8];
#pragma unroll
        for (int rg = 0; rg < 2; ++rg)
#pragma unroll
            for (int ct = 0; ct < 2; ++ct) {
                f32x4 acc = {0.f, 0.f, 0.f, 0.f};
#pragma unroll
                for (int kk = 0; kk < 4; ++kk)
                    acc = __builtin_amdgcn_mfma_f32_16x16x32_bf16(A2[rg][kk], B2[ct][kk], acc, 0, 0, 0);
#pragma unroll
                for (int r = 0; r < 4; ++r)
                    xb[1][rg * 16 + lg * 4 + r][wave * 32 + ct * 16 + lr] = f2bf(acc[r] + b2v[ct]);
            }
        lds_barrier();                      // barrier2
        // stage prefetched E -> Eb[cur^1] (read at top of t+1, after barrier3)
        {
            uint4 w0 = make_uint4(pk2bf(nf0.x, nf0.y), pk2bf(nf0.z, nf0.w),
                                  pk2bf(nf1.x, nf1.y), pk2bf(nf1.z, nf1.w));
            uint4 w1 = make_uint4(pk2bf(nf2.x, nf2.y), pk2bf(nf2.z, nf2.w),
                                  pk2bf(nf3.x, nf3.y), pk2bf(nf3.z, nf3.w));
            uint4* wp = (uint4*)&Eb[cur ^ 1][srow][schunk * 16];
            wp[0] = w0; wp[1] = w1;
        }
        // G3/G4: scale = sigmoid(x@WB^T+bB), shift = x@WC^T+bC; msg; scatter
        bf16x8 A3[2][4];
#pragma unroll
        for (int rg = 0; rg < 2; ++rg)
#pragma unroll
            for (int kk = 0; kk < 4; ++kk)
                A3[rg][kk] = *(const bf16x8*)&xb[1][rg * 16 + lr][kk * 32 + lg * 8];
#pragma unroll
        for (int rg = 0; rg < 2; ++rg)
#pragma unroll
            for (int ct = 0; ct < 2; ++ct) {
                f32x4 aB = {0.f, 0.f, 0.f, 0.f}, aC = {0.f, 0.f, 0.f, 0.f};
#pragma unroll
                for (int kk = 0; kk < 4; ++kk) {
                    aB = __builtin_amdgcn_mfma_f32_16x16x32_bf16(A3[rg][kk], B3[ct][kk], aB, 0, 0, 0);
                    aC = __builtin_amdgcn_mfma_f32_16x16x32_bf16(A3[rg][kk], B4[ct][kk], aC, 0, 0, 0);
                }
                const int col = wave * 32 + ct * 16 + lr;
#pragma unroll
                for (int r = 0; r < 4; ++r) {
                    int idx = rg * 4 + r;
                    float sc = 1.f / (1.f + __expf(-(aB[r] + b3v[ct])));
                    float sh = aC[r] + b4v[ct];
                    float v = bf2f(gv[rg * 16 + lg * 4 + r][col]);
                    float msg = sc * v + sh;
                    if (val[idx])
                        unsafeAtomicAdd(out + (size_t)di[idx] * DD + col, msg);
                }
            }
        lds_barrier();                      // barrier3: Eb[cur^1] writes vs t+1 reads
        cur ^= 1;
    }
}

extern "C" void kernel_launch(void* const* d_in, const int* in_sizes, int n_in,
                              void* d_out, int out_size, void* d_ws, size_t ws_size,
                              hipStream_t stream) {
    const float* V   = (const float*)d_in[0];
    const float* E   = (const float*)d_in[1];
    const int*   src = (const int*)d_in[2];
    const int*   dst = (const int*)d_in[3];
    const float* Wp1 = (const float*)d_in[4];  const float* bp1 = (const float*)d_in[5];
    const float* Wp2 = (const float*)d_in[6];  const float* bp2 = (const float*)d_in[7];
    const float* WA1 = (const float*)d_in[8];  const float* bA1 = (const float*)d_in[9];
    const float* WA2 = (const float*)d_in[10]; const float* bA2 = (const float*)d_in[11];
    const float* WB  = (const float*)d_in[12]; const float* bB  = (const float*)d_in[13];
    const float* WC  = (const float*)d_in[14]; const float* bC  = (const float*)d_in[15];
    float* out = (float*)d_out;

    const int nN = in_sizes[0] / DD;
    const int nE = in_sizes[1] / DD;
    const int nTilesN = (nN + 31) / 32;
    const int nTilesE = (nE + 31) / 32;

    unsigned short* wbf = (unsigned short*)d_ws;                       // 6*16384 u16
    unsigned short* Vp  = (unsigned short*)((char*)d_ws + 196608);     // nN*128 u16

    hipMemsetAsync(d_out, 0, (size_t)out_size * sizeof(float), stream);
    k_convert<<<(6 * 16384 + 255) / 256, 256, 0, stream>>>(Wp1, Wp2, WA1, WA2, WB, WC, wbf);
    int gN = nTilesN < 512 ? nTilesN : 512;
    k_nodes<<<gN, 256, 0, stream>>>(V, wbf, bp1, bp2, Vp, nN, nTilesN);
    int gE = nTilesE < 512 ? nTilesE : 512;   // 2 blocks/CU resident, persistent
    k_edges<<<gE, 256, 0, stream>>>(E, src, dst, wbf, bA1, bA2, bB, bC, Vp, out, nE, nTilesE);
}